// Round 12
// baseline (2434.588 us; speedup 1.0000x reference)
//
#include <hip/hip_runtime.h>
#include <hip/hip_bf16.h>

#define N_NODES 100000
#define N_EDGES 3200000
#define IN_CH   256
#define OUT_CH  128

#define RPB 64                      // rows per bucket
#define NBUCKET 1563                // ceil(100000/64)
#define NBLK 256                    // partition chunks (one per block)
#define PART_T 1024                 // histA threads per block
#define SS_T 1024                   // sortscatter threads per block
#define CHUNK (N_EDGES / NBLK)      // 12500 edges per block
#define CHUNK4 (CHUNK / 4)          // 3125 iv4 per block
#define CAP 2816                    // LDS edge cap per bucket (mu+17sigma)
#define AGG_T 512                   // bucket_agg threads
#define QREG 6                      // ceil(CAP/AGG_T)
#define NSLICE 13                   // col slice = col>>13 (8192 nodes = 2MB hb)

typedef int   iv4 __attribute__((ext_vector_type(4)));
typedef float fv4 __attribute__((ext_vector_type(4)));
typedef short bf16x8 __attribute__((ext_vector_type(8)));
typedef float f32x4 __attribute__((ext_vector_type(4)));
typedef unsigned long long u64;
typedef unsigned short ushort_t;

// round-to-nearest-even f32 -> bf16 (as u16 in low bits)
__device__ __forceinline__ unsigned bfr(float f) {
  unsigned u = __float_as_uint(f);
  return (u + 0x7FFFu + ((u >> 16) & 1u)) >> 16;
}

// ---------------- W prep: wt[col][k] bf16 <- W[k][col] fp32 ------------------
__global__ __launch_bounds__(256) void wt_prep_kernel(
    const float* __restrict__ W, ushort_t* __restrict__ wt) {
  const int T = blockIdx.x * 256 + threadIdx.x;  // 0..8191
  const int col = T >> 6;
  const int k0 = (T & 63) * 4;
  uint2 pk;
  pk.x = bfr(W[(size_t)(k0 + 0) * OUT_CH + col]) |
         (bfr(W[(size_t)(k0 + 1) * OUT_CH + col]) << 16);
  pk.y = bfr(W[(size_t)(k0 + 2) * OUT_CH + col]) |
         (bfr(W[(size_t)(k0 + 3) * OUT_CH + col]) << 16);
  *reinterpret_cast<uint2*>(wt + (size_t)col * IN_CH + k0) = pk;
}

// ---------------- GEMM (MFMA bf16): hb = bf16(x @ W + b) ---------------------
#define GR 32

__global__ __launch_bounds__(256) void gemm_mfma_kernel(
    const float* __restrict__ x, const ushort_t* __restrict__ wt,
    const float* __restrict__ b, ushort_t* __restrict__ hb) {
  __shared__ alignas(16) char xs[GR * 512];    // 16 KB: [row][k]
  __shared__ alignas(16) char ws[128 * 512];   // 64 KB: [col][k]

  const int tid = threadIdx.x;
  const int row0 = blockIdx.x * GR;

#pragma unroll
  for (int it = 0; it < 8; ++it) {
    int f = it * 256 + tid;
    int r = f >> 6, k4 = f & 63;
    fv4 v = *reinterpret_cast<const fv4*>(x + (size_t)(row0 + r) * IN_CH + k4 * 4);
    uint2 pk;
    pk.x = bfr(v.x) | (bfr(v.y) << 16);
    pk.y = bfr(v.z) | (bfr(v.w) << 16);
    unsigned off = (unsigned)(r * 512) + (((unsigned)(k4 * 8)) ^ ((unsigned)(r & 7) << 4));
    *reinterpret_cast<uint2*>(xs + off) = pk;
  }
#pragma unroll
  for (int it = 0; it < 16; ++it) {
    int f = it * 256 + tid;
    int col = f >> 5, ch = f & 31;
    bf16x8 v = *reinterpret_cast<const bf16x8*>(wt + (size_t)col * IN_CH + ch * 8);
    unsigned off = (unsigned)(col * 512) + (((unsigned)(ch * 16)) ^ ((unsigned)(col & 7) << 4));
    *reinterpret_cast<bf16x8*>(ws + off) = v;
  }
  __syncthreads();

  const int w = tid >> 6, l = tid & 63;
  const int lr = l & 15, lk = l >> 4;
  const int arow = (w & 1) * 16 + lr;
  const int cb = (w >> 1) * 64;

  f32x4 acc[4];
#pragma unroll
  for (int n = 0; n < 4; ++n) {
    int c0 = cb + n * 16 + lk * 4;
    acc[n] = (f32x4){b[c0], b[c0 + 1], b[c0 + 2], b[c0 + 3]};
  }

  const unsigned axm = (unsigned)(arow & 7) << 4;
#pragma unroll
  for (int kk = 0; kk < 8; ++kk) {
    bf16x8 af = *reinterpret_cast<const bf16x8*>(
        xs + (unsigned)(arow * 512) + (((unsigned)(kk * 64 + lk * 16)) ^ axm));
#pragma unroll
    for (int n = 0; n < 4; ++n) {
      int bcol = cb + n * 16 + lr;
      bf16x8 bf_ = *reinterpret_cast<const bf16x8*>(
          ws + (unsigned)(bcol * 512) +
          (((unsigned)(kk * 64 + lk * 16)) ^ ((unsigned)(bcol & 7) << 4)));
      acc[n] = __builtin_amdgcn_mfma_f32_16x16x32_bf16(bf_, af, acc[n], 0, 0, 0);
    }
  }

  const int grow = row0 + arow;
#pragma unroll
  for (int n = 0; n < 4; ++n) {
    int c0 = cb + n * 16 + lk * 4;
    uint2 pk;
    pk.x = bfr(acc[n][0]) | (bfr(acc[n][1]) << 16);
    pk.y = bfr(acc[n][2]) | (bfr(acc[n][3]) << 16);
    *reinterpret_cast<uint2*>(hb + (size_t)grow * OUT_CH + c0) = pk;
  }
}

// ---------------- histA: per-block bucket histogram (bucket-major out) -------
__global__ __launch_bounds__(PART_T) void histA_kernel(
    const int* __restrict__ erow, int* __restrict__ histA) {
  __shared__ int hcnt[NBUCKET];
  const int blk = blockIdx.x, tid = threadIdx.x;
  for (int i = tid; i < NBUCKET; i += PART_T) hcnt[i] = 0;
  __syncthreads();
  const iv4* er4 = reinterpret_cast<const iv4*>(erow) + blk * CHUNK4;
  for (int i = tid; i < CHUNK4; i += PART_T) {
    iv4 r4 = __builtin_nontemporal_load(er4 + i);
    atomicAdd(&hcnt[r4.x >> 6], 1);
    atomicAdd(&hcnt[r4.y >> 6], 1);
    atomicAdd(&hcnt[r4.z >> 6], 1);
    atomicAdd(&hcnt[r4.w >> 6], 1);
  }
  __syncthreads();
  for (int b2 = tid; b2 < NBUCKET; b2 += PART_T)
    histA[b2 * NBLK + blk] = hcnt[b2];
}

// ---------------- 3-phase exclusive scan over NBUCKET*NBLK = 400128 ---------
__global__ __launch_bounds__(256) void scanA_partial(
    const int* __restrict__ a, int* __restrict__ bsum) {
  __shared__ int s[256];
  const int t = threadIdx.x;
  s[t] = a[blockIdx.x * 256 + t];
  __syncthreads();
#pragma unroll
  for (int d = 128; d > 0; d >>= 1) {
    if (t < d) s[t] += s[t + d];
    __syncthreads();
  }
  if (t == 0) bsum[blockIdx.x] = s[0];
}

// single block, 1024 thr, 2 elems/thread -> handles NBUCKET=1563
__global__ __launch_bounds__(1024) void scanA_bsums(int* __restrict__ bsum) {
  __shared__ int s[1024];
  const int t = threadIdx.x;
  const int i0 = 2 * t, i1 = 2 * t + 1;
  const int v0 = (i0 < NBUCKET) ? bsum[i0] : 0;
  const int v1 = (i1 < NBUCKET) ? bsum[i1] : 0;
  s[t] = v0 + v1;
  __syncthreads();
  for (int d = 1; d < 1024; d <<= 1) {
    int u = (t >= d) ? s[t - d] : 0;
    __syncthreads();
    s[t] += u;
    __syncthreads();
  }
  const int ex = (t == 0) ? 0 : s[t - 1];
  if (i0 < NBUCKET) bsum[i0] = ex;
  if (i1 < NBUCKET) bsum[i1] = ex + v0;
}

__global__ __launch_bounds__(256) void scanA_apply(
    int* __restrict__ a, const int* __restrict__ bsum) {
  __shared__ int s[256];
  const int t = threadIdx.x;
  const int idx = blockIdx.x * 256 + t;
  const int v = a[idx];
  s[t] = v;
  __syncthreads();
  for (int d = 1; d < 256; d <<= 1) {
    int u = (t >= d) ? s[t - d] : 0;
    __syncthreads();
    s[t] += u;
    __syncthreads();
  }
  a[idx] = s[t] - v + bsum[blockIdx.x];  // exclusive
}

// ---------------- sortscatter: local counting sort + monotone coalesced flush
__global__ __launch_bounds__(SS_T) void sortscatter_kernel(
    const int* __restrict__ erow, const int* __restrict__ ecol,
    const float* __restrict__ eval, const int* __restrict__ scanA,
    u64* __restrict__ tmp) {
  __shared__ u64 sorted_q[CHUNK];        // 100000 B
  __shared__ ushort_t bkt[CHUNK];        // 25000 B
  __shared__ int cursor[NBUCKET];        // 6252 B
  __shared__ int delta[NBUCKET];         // 6252 B

  const int blk = blockIdx.x, tid = threadIdx.x;
  int* sarr = reinterpret_cast<int*>(sorted_q);  // scan scratch (pre-scatter)

  const int b0 = 2 * tid, b1 = 2 * tid + 1;
  int c0 = 0, c1 = 0, g0 = 0, g1 = 0;
  if (b0 < NBUCKET) {
    int idx = b0 * NBLK + blk;
    g0 = scanA[idx];
    int nxt = (idx + 1 < NBUCKET * NBLK) ? scanA[idx + 1] : N_EDGES;
    c0 = nxt - g0;
  }
  if (b1 < NBUCKET) {
    int idx = b1 * NBLK + blk;
    g1 = scanA[idx];
    int nxt = (idx + 1 < NBUCKET * NBLK) ? scanA[idx + 1] : N_EDGES;
    c1 = nxt - g1;
  }
  sarr[tid] = c0 + c1;
  __syncthreads();
  for (int d = 1; d < SS_T; d <<= 1) {
    int v = (tid >= d) ? sarr[tid - d] : 0;
    __syncthreads();
    sarr[tid] += v;
    __syncthreads();
  }
  const int pref = (tid == 0) ? 0 : sarr[tid - 1];
  __syncthreads();  // done with sarr (sorted_q reused below)
  if (b0 < NBUCKET) { cursor[b0] = pref;      delta[b0] = g0 - pref; }
  if (b1 < NBUCKET) { cursor[b1] = pref + c0; delta[b1] = g1 - (pref + c0); }
  __syncthreads();

  const iv4* er4 = reinterpret_cast<const iv4*>(erow) + blk * CHUNK4;
  const iv4* ec4 = reinterpret_cast<const iv4*>(ecol) + blk * CHUNK4;
  const fv4* ev4 = reinterpret_cast<const fv4*>(eval) + blk * CHUNK4;
  for (int i = tid; i < CHUNK4; i += SS_T) {
    iv4 r4 = __builtin_nontemporal_load(er4 + i);
    iv4 c4 = __builtin_nontemporal_load(ec4 + i);
    fv4 v4 = __builtin_nontemporal_load(ev4 + i);
#pragma unroll
    for (int j = 0; j < 4; ++j) {
      int r = r4[j];
      int bb = r >> 6;
      int pos = atomicAdd(&cursor[bb], 1);
      sorted_q[pos] = ((u64)(unsigned)__float_as_int(v4[j]) << 32) |
                      ((unsigned)(r & 63) << 17) | (unsigned)c4[j];
      bkt[pos] = (ushort_t)bb;
    }
  }
  __syncthreads();

  for (int i = tid; i < CHUNK; i += SS_T) {
    u64 q = sorted_q[i];
    int dst = i + delta[bkt[i]];
    __builtin_nontemporal_store(q, tmp + dst);
  }
}

// ---------------- bucket_agg: slice-sorted stream + LDS fp32 accumulators ----
// Counting-sort bucket edges by col-slice only (13 keys). All waves stream the
// slice-ordered list with stride 8 (uniform -> lockstep slice sweep, ~2MB live
// hb window = L2-resident) and accumulate into a 64x128 fp32 LDS array via
// shared-memory atomicAdd (no row segmentation, no per-segment overhead).
__global__ __launch_bounds__(AGG_T) void bucket_agg_kernel(
    const ushort_t* __restrict__ hb, const u64* __restrict__ tmp,
    const int* __restrict__ scanA, float* __restrict__ out) {
  __shared__ u64 eds[CAP];               // 22528 B slice-sorted edges
  __shared__ float accf[RPB * OUT_CH];   // 32768 B fp32 accumulators
  __shared__ int scnt[NSLICE];
  __shared__ int scur[NSLICE];

  const int bkt = blockIdx.x, tid = threadIdx.x;
  const int base = scanA[bkt * NBLK];
  const int end = (bkt == NBUCKET - 1) ? N_EDGES : scanA[(bkt + 1) * NBLK];
  const int cnt = end - base;
  const int row0 = bkt * RPB;
  const unsigned* __restrict__ h32 = reinterpret_cast<const unsigned*>(hb);
  const int w = tid >> 6, lane = tid & 63;

  if (cnt <= CAP) {
    // zero accumulators + slice counters
    for (int i = tid; i < RPB * OUT_CH / 4; i += AGG_T)
      reinterpret_cast<f32x4*>(accf)[i] = (f32x4){0.f, 0.f, 0.f, 0.f};
    if (tid < NSLICE) scnt[tid] = 0;
    __syncthreads();

    u64 qreg[QREG];
#pragma unroll
    for (int j = 0; j < QREG; ++j) {
      int i = j * AGG_T + tid;
      if (i < cnt) {
        u64 q = __builtin_nontemporal_load(tmp + base + i);
        qreg[j] = q;
        atomicAdd(&scnt[(unsigned)(q >> 13) & 0x0Fu], 1);
      }
    }
    __syncthreads();

    if (tid == 0) {
      int run = 0;
#pragma unroll
      for (int s = 0; s < NSLICE; ++s) {
        int c = scnt[s];
        scur[s] = run;
        run += c;
      }
    }
    __syncthreads();

#pragma unroll
    for (int j = 0; j < QREG; ++j) {
      int i = j * AGG_T + tid;
      if (i < cnt) {
        u64 q = qreg[j];
        int pos = atomicAdd(&scur[(unsigned)(q >> 13) & 0x0Fu], 1);
        eds[pos] = q;
      }
    }
    __syncthreads();

    // stream: wave w takes edges w, w+8, w+16, ... (8-deep unroll)
    int e = w;
    for (; e + 56 < cnt; e += 64) {
      u64 q[8];
#pragma unroll
      for (int j = 0; j < 8; ++j) q[j] = eds[e + j * 8];
      unsigned g[8];
#pragma unroll
      for (int j = 0; j < 8; ++j)
        g[j] = h32[(size_t)(unsigned)(q[j] & 0x1FFFFu) * 64 + lane];
#pragma unroll
      for (int j = 0; j < 8; ++j) {
        float v = __int_as_float((int)(q[j] >> 32));
        int row = (int)((q[j] >> 17) & 63u);
        float* a = accf + row * OUT_CH + lane * 2;
        atomicAdd(a + 0, v * __uint_as_float(g[j] << 16));
        atomicAdd(a + 1, v * __uint_as_float(g[j] & 0xFFFF0000u));
      }
    }
    for (; e < cnt; e += 8) {
      u64 q = eds[e];
      unsigned g = h32[(size_t)(unsigned)(q & 0x1FFFFu) * 64 + lane];
      float v = __int_as_float((int)(q >> 32));
      int row = (int)((q >> 17) & 63u);
      float* a = accf + row * OUT_CH + lane * 2;
      atomicAdd(a + 0, v * __uint_as_float(g << 16));
      atomicAdd(a + 1, v * __uint_as_float(g & 0xFFFF0000u));
    }
    __syncthreads();

    // flush: wave w owns rows [w*8, w*8+8)
#pragma unroll
    for (int ri = 0; ri < 8; ++ri) {
      const int row = w * 8 + ri;
      const int grow = row0 + row;
      if (grow < N_NODES) {
        float2 o = reinterpret_cast<const float2*>(accf)[row * 64 + lane];
        reinterpret_cast<float2*>(out)[(size_t)grow * 64 + lane] = o;
      }
    }
  } else {
    // fallback (statistically unreachable): zero rows then global atomics
    for (int i = tid; i < RPB * 64; i += AGG_T) {
      int grow = row0 + (i >> 6);
      if (grow < N_NODES)
        reinterpret_cast<float2*>(out)[(size_t)grow * 64 + (i & 63)] =
            make_float2(0.f, 0.f);
    }
    __syncthreads();
    for (int i = w; i < cnt; i += AGG_T / 64) {
      u64 q = tmp[base + i];
      int r = (unsigned)(q >> 17) & 63u;
      unsigned col = (unsigned)(q & 0x1FFFFu);
      float v = __int_as_float((int)(q >> 32));
      unsigned u = h32[(size_t)col * 64 + lane];
      if (row0 + r < N_NODES) {
        atomicAdd(out + (size_t)(row0 + r) * OUT_CH + lane * 2,
                  v * __uint_as_float(u << 16));
        atomicAdd(out + (size_t)(row0 + r) * OUT_CH + lane * 2 + 1,
                  v * __uint_as_float(u & 0xFFFF0000u));
      }
    }
  }
}

extern "C" void kernel_launch(void* const* d_in, const int* in_sizes, int n_in,
                              void* d_out, int out_size, void* d_ws,
                              size_t ws_size, hipStream_t stream) {
  const float* x    = (const float*)d_in[0];
  const float* W    = (const float*)d_in[1];
  const float* b    = (const float*)d_in[2];
  const int* erow   = (const int*)d_in[3];
  const int* ecol   = (const int*)d_in[4];
  const float* eval = (const float*)d_in[5];
  float* out = (float*)d_out;

  // Workspace (~52.9 MB):
  //   hb:    [0, 25.6MB)          N_NODES*OUT_CH bf16
  //   tmp:   [25.6MB, +25.6MB)    N_EDGES u64 (bucket-partitioned edges)
  //   scanA: [51.2MB, +1600512B)  NBUCKET*NBLK ints
  //   bsum:  [+6252B]             NBUCKET ints
  //   wt:    [+64KB]              W^T bf16 [128][256]
  char* wsb = (char*)d_ws;
  ushort_t* hb  = (ushort_t*)(wsb);
  u64* tmp      = (u64*)(wsb + 25600000);
  int* scanA    = (int*)(wsb + 51200000);
  int* bsum     = (int*)(wsb + 52800512);
  ushort_t* wt  = (ushort_t*)(wsb + 52806764 + 4);  // align 8

  // 1) h = x @ W + b  (bf16 MFMA)
  wt_prep_kernel<<<32, 256, 0, stream>>>(W, wt);
  gemm_mfma_kernel<<<N_NODES / GR, 256, 0, stream>>>(x, wt, b, hb);

  // 2) bucket partition (1563 buckets of 64 rows)
  histA_kernel<<<NBLK, PART_T, 0, stream>>>(erow, scanA);
  scanA_partial<<<NBUCKET, 256, 0, stream>>>(scanA, bsum);
  scanA_bsums<<<1, 1024, 0, stream>>>(bsum);
  scanA_apply<<<NBUCKET, 256, 0, stream>>>(scanA, bsum);
  sortscatter_kernel<<<NBLK, SS_T, 0, stream>>>(erow, ecol, eval, scanA, tmp);

  // 3) fused slice-sorted stream + LDS fp32 accumulate + store
  bucket_agg_kernel<<<NBUCKET, AGG_T, 0, stream>>>(hb, tmp, scanA, out);
}

// Round 13
// 198.807 us; speedup vs baseline: 12.2460x; 12.2460x over previous
//
#include <hip/hip_runtime.h>
#include <hip/hip_bf16.h>

#define N_NODES 100000
#define N_EDGES 3200000
#define IN_CH   256
#define OUT_CH  128

#define RPB 64                      // rows per bucket
#define NBUCKET 1563                // ceil(100000/64)
#define NBLK 256                    // partition chunks (one per block)
#define SS_T 1024                   // sortscatter threads per block
#define CHUNK (N_EDGES / NBLK)      // 12500 edges per block
#define CHUNK4 (CHUNK / 4)          // 3125 iv4 per block
#define CAP 2816                    // LDS edge cap per bucket (mu+17sigma)
#define AGG_T 512                   // bucket_agg threads
#define QREG 6                      // ceil(CAP/AGG_T)
#define GR 32                       // gemm rows per block
#define GEMM_BLKS (N_NODES / GR)    // 3125

typedef int   iv4 __attribute__((ext_vector_type(4)));
typedef float fv4 __attribute__((ext_vector_type(4)));
typedef short bf16x8 __attribute__((ext_vector_type(8)));
typedef float f32x4 __attribute__((ext_vector_type(4)));
typedef unsigned long long u64;
typedef unsigned short ushort_t;

// round-to-nearest-even f32 -> bf16 (as u16 in low bits)
__device__ __forceinline__ unsigned bfr(float f) {
  unsigned u = __float_as_uint(f);
  return (u + 0x7FFFu + ((u >> 16) & 1u)) >> 16;
}

// ---------------- W prep: wt[col][k] bf16 <- W[k][col] fp32 ------------------
__global__ __launch_bounds__(256) void wt_prep_kernel(
    const float* __restrict__ W, ushort_t* __restrict__ wt) {
  const int T = blockIdx.x * 256 + threadIdx.x;  // 0..8191
  const int col = T >> 6;
  const int k0 = (T & 63) * 4;
  uint2 pk;
  pk.x = bfr(W[(size_t)(k0 + 0) * OUT_CH + col]) |
         (bfr(W[(size_t)(k0 + 1) * OUT_CH + col]) << 16);
  pk.y = bfr(W[(size_t)(k0 + 2) * OUT_CH + col]) |
         (bfr(W[(size_t)(k0 + 3) * OUT_CH + col]) << 16);
  *reinterpret_cast<uint2*>(wt + (size_t)col * IN_CH + k0) = pk;
}

// ---------------- fused: blocks [0,NBLK) = histA; [NBLK,+3125) = GEMM --------
// hist blocks first so they start immediately and overlap the longer GEMM.
__global__ __launch_bounds__(256) void gemm_hist_kernel(
    const float* __restrict__ x, const ushort_t* __restrict__ wt,
    const float* __restrict__ b, ushort_t* __restrict__ hb,
    const int* __restrict__ erow, int* __restrict__ histA) {
  __shared__ alignas(16) char smem[81920];  // gemm: xs 16KB + ws 64KB; hist: hcnt

  const int tid = threadIdx.x;

  if (blockIdx.x < NBLK) {
    // ---------------- histA path ----------------
    int* hcnt = reinterpret_cast<int*>(smem);
    const int blk = blockIdx.x;
    for (int i = tid; i < NBUCKET; i += 256) hcnt[i] = 0;
    __syncthreads();
    const iv4* er4 = reinterpret_cast<const iv4*>(erow) + blk * CHUNK4;
    for (int i = tid; i < CHUNK4; i += 256) {
      iv4 r4 = __builtin_nontemporal_load(er4 + i);
      atomicAdd(&hcnt[r4.x >> 6], 1);
      atomicAdd(&hcnt[r4.y >> 6], 1);
      atomicAdd(&hcnt[r4.z >> 6], 1);
      atomicAdd(&hcnt[r4.w >> 6], 1);
    }
    __syncthreads();
    for (int b2 = tid; b2 < NBUCKET; b2 += 256)
      histA[b2 * NBLK + blk] = hcnt[b2];
    return;
  }

  // ---------------- GEMM path ----------------
  char* xs = smem;            // [row][k] bf16, 32*512
  char* ws = smem + 16384;    // [col][k] bf16, 128*512
  const int row0 = (blockIdx.x - NBLK) * GR;

#pragma unroll
  for (int it = 0; it < 8; ++it) {
    int f = it * 256 + tid;
    int r = f >> 6, k4 = f & 63;
    fv4 v = *reinterpret_cast<const fv4*>(x + (size_t)(row0 + r) * IN_CH + k4 * 4);
    uint2 pk;
    pk.x = bfr(v.x) | (bfr(v.y) << 16);
    pk.y = bfr(v.z) | (bfr(v.w) << 16);
    unsigned off = (unsigned)(r * 512) + (((unsigned)(k4 * 8)) ^ ((unsigned)(r & 7) << 4));
    *reinterpret_cast<uint2*>(xs + off) = pk;
  }
#pragma unroll
  for (int it = 0; it < 16; ++it) {
    int f = it * 256 + tid;
    int col = f >> 5, ch = f & 31;
    bf16x8 v = *reinterpret_cast<const bf16x8*>(wt + (size_t)col * IN_CH + ch * 8);
    unsigned off = (unsigned)(col * 512) + (((unsigned)(ch * 16)) ^ ((unsigned)(col & 7) << 4));
    *reinterpret_cast<bf16x8*>(ws + off) = v;
  }
  __syncthreads();

  const int w = tid >> 6, l = tid & 63;
  const int lr = l & 15, lk = l >> 4;
  const int arow = (w & 1) * 16 + lr;
  const int cb = (w >> 1) * 64;

  f32x4 acc[4];
#pragma unroll
  for (int n = 0; n < 4; ++n) {
    int c0 = cb + n * 16 + lk * 4;
    acc[n] = (f32x4){b[c0], b[c0 + 1], b[c0 + 2], b[c0 + 3]};
  }

  const unsigned axm = (unsigned)(arow & 7) << 4;
#pragma unroll
  for (int kk = 0; kk < 8; ++kk) {
    bf16x8 af = *reinterpret_cast<const bf16x8*>(
        xs + (unsigned)(arow * 512) + (((unsigned)(kk * 64 + lk * 16)) ^ axm));
#pragma unroll
    for (int n = 0; n < 4; ++n) {
      int bcol = cb + n * 16 + lr;
      bf16x8 bf_ = *reinterpret_cast<const bf16x8*>(
          ws + (unsigned)(bcol * 512) +
          (((unsigned)(kk * 64 + lk * 16)) ^ ((unsigned)(bcol & 7) << 4)));
      acc[n] = __builtin_amdgcn_mfma_f32_16x16x32_bf16(bf_, af, acc[n], 0, 0, 0);
    }
  }

  const int grow = row0 + arow;
#pragma unroll
  for (int n = 0; n < 4; ++n) {
    int c0 = cb + n * 16 + lk * 4;
    uint2 pk;
    pk.x = bfr(acc[n][0]) | (bfr(acc[n][1]) << 16);
    pk.y = bfr(acc[n][2]) | (bfr(acc[n][3]) << 16);
    *reinterpret_cast<uint2*>(hb + (size_t)grow * OUT_CH + c0) = pk;
  }
}

// ---------------- 3-phase exclusive scan over NBUCKET*NBLK = 400128 ---------
__global__ __launch_bounds__(256) void scanA_partial(
    const int* __restrict__ a, int* __restrict__ bsum) {
  __shared__ int s[256];
  const int t = threadIdx.x;
  s[t] = a[blockIdx.x * 256 + t];
  __syncthreads();
#pragma unroll
  for (int d = 128; d > 0; d >>= 1) {
    if (t < d) s[t] += s[t + d];
    __syncthreads();
  }
  if (t == 0) bsum[blockIdx.x] = s[0];
}

// single block, 1024 thr, 2 elems/thread -> handles NBUCKET=1563
__global__ __launch_bounds__(1024) void scanA_bsums(int* __restrict__ bsum) {
  __shared__ int s[1024];
  const int t = threadIdx.x;
  const int i0 = 2 * t, i1 = 2 * t + 1;
  const int v0 = (i0 < NBUCKET) ? bsum[i0] : 0;
  const int v1 = (i1 < NBUCKET) ? bsum[i1] : 0;
  s[t] = v0 + v1;
  __syncthreads();
  for (int d = 1; d < 1024; d <<= 1) {
    int u = (t >= d) ? s[t - d] : 0;
    __syncthreads();
    s[t] += u;
    __syncthreads();
  }
  const int ex = (t == 0) ? 0 : s[t - 1];
  if (i0 < NBUCKET) bsum[i0] = ex;
  if (i1 < NBUCKET) bsum[i1] = ex + v0;
}

__global__ __launch_bounds__(256) void scanA_apply(
    int* __restrict__ a, const int* __restrict__ bsum) {
  __shared__ int s[256];
  const int t = threadIdx.x;
  const int idx = blockIdx.x * 256 + t;
  const int v = a[idx];
  s[t] = v;
  __syncthreads();
  for (int d = 1; d < 256; d <<= 1) {
    int u = (t >= d) ? s[t - d] : 0;
    __syncthreads();
    s[t] += u;
    __syncthreads();
  }
  a[idx] = s[t] - v + bsum[blockIdx.x];  // exclusive
}

// ---------------- sortscatter: local counting sort + monotone coalesced flush
__global__ __launch_bounds__(SS_T) void sortscatter_kernel(
    const int* __restrict__ erow, const int* __restrict__ ecol,
    const float* __restrict__ eval, const int* __restrict__ scanA,
    u64* __restrict__ tmp) {
  __shared__ u64 sorted_q[CHUNK];        // 100000 B
  __shared__ ushort_t bkt[CHUNK];        // 25000 B
  __shared__ int cursor[NBUCKET];        // 6252 B
  __shared__ int delta[NBUCKET];         // 6252 B

  const int blk = blockIdx.x, tid = threadIdx.x;
  int* sarr = reinterpret_cast<int*>(sorted_q);  // scan scratch (pre-scatter)

  const int b0 = 2 * tid, b1 = 2 * tid + 1;
  int c0 = 0, c1 = 0, g0 = 0, g1 = 0;
  if (b0 < NBUCKET) {
    int idx = b0 * NBLK + blk;
    g0 = scanA[idx];
    int nxt = (idx + 1 < NBUCKET * NBLK) ? scanA[idx + 1] : N_EDGES;
    c0 = nxt - g0;
  }
  if (b1 < NBUCKET) {
    int idx = b1 * NBLK + blk;
    g1 = scanA[idx];
    int nxt = (idx + 1 < NBUCKET * NBLK) ? scanA[idx + 1] : N_EDGES;
    c1 = nxt - g1;
  }
  sarr[tid] = c0 + c1;
  __syncthreads();
  for (int d = 1; d < SS_T; d <<= 1) {
    int v = (tid >= d) ? sarr[tid - d] : 0;
    __syncthreads();
    sarr[tid] += v;
    __syncthreads();
  }
  const int pref = (tid == 0) ? 0 : sarr[tid - 1];
  __syncthreads();  // done with sarr (sorted_q reused below)
  if (b0 < NBUCKET) { cursor[b0] = pref;      delta[b0] = g0 - pref; }
  if (b1 < NBUCKET) { cursor[b1] = pref + c0; delta[b1] = g1 - (pref + c0); }
  __syncthreads();

  const iv4* er4 = reinterpret_cast<const iv4*>(erow) + blk * CHUNK4;
  const iv4* ec4 = reinterpret_cast<const iv4*>(ecol) + blk * CHUNK4;
  const fv4* ev4 = reinterpret_cast<const fv4*>(eval) + blk * CHUNK4;
  for (int i = tid; i < CHUNK4; i += SS_T) {
    iv4 r4 = __builtin_nontemporal_load(er4 + i);
    iv4 c4 = __builtin_nontemporal_load(ec4 + i);
    fv4 v4 = __builtin_nontemporal_load(ev4 + i);
#pragma unroll
    for (int j = 0; j < 4; ++j) {
      int r = r4[j];
      int bb = r >> 6;
      int pos = atomicAdd(&cursor[bb], 1);
      sorted_q[pos] = ((u64)(unsigned)__float_as_int(v4[j]) << 32) |
                      ((unsigned)(r & 63) << 17) | (unsigned)c4[j];
      bkt[pos] = (ushort_t)bb;
    }
  }
  __syncthreads();

  for (int i = tid; i < CHUNK; i += SS_T) {
    u64 q = sorted_q[i];
    int dst = i + delta[bkt[i]];
    __builtin_nontemporal_store(q, tmp + dst);
  }
}

// ---------------- bucket_agg: in-LDS row sort + aggregate + store ------------
// (r10 structure: row-sorted segments avg ~32 edges, register accumulation;
//  8-deep unroll for more gathers in flight)
__global__ __launch_bounds__(AGG_T) void bucket_agg_kernel(
    const ushort_t* __restrict__ hb, const u64* __restrict__ tmp,
    const int* __restrict__ scanA, float* __restrict__ out) {
  __shared__ u64 eds[CAP];            // 22.5 KB sorted edges
  __shared__ int rcnt[RPB];
  __shared__ int rstart[RPB + 1];
  __shared__ int rcur[RPB];
  __shared__ int sscan[RPB];

  const int bkt = blockIdx.x, tid = threadIdx.x;
  const int base = scanA[bkt * NBLK];
  const int end = (bkt == NBUCKET - 1) ? N_EDGES : scanA[(bkt + 1) * NBLK];
  const int cnt = end - base;
  const int row0 = bkt * RPB;
  const unsigned* __restrict__ h32 = reinterpret_cast<const unsigned*>(hb);
  const int w = tid >> 6, lane = tid & 63;

  if (cnt <= CAP) {
    if (tid < RPB) rcnt[tid] = 0;
    __syncthreads();

    u64 qreg[QREG];
#pragma unroll
    for (int j = 0; j < QREG; ++j) {
      int i = j * AGG_T + tid;
      if (i < cnt) {
        qreg[j] = __builtin_nontemporal_load(tmp + base + i);
        atomicAdd(&rcnt[(unsigned)(qreg[j] >> 17) & 63u], 1);
      }
    }
    __syncthreads();

    // exclusive scan of 64 row counts
    if (tid < RPB) sscan[tid] = rcnt[tid];
    __syncthreads();
    for (int d = 1; d < RPB; d <<= 1) {
      int v = (tid < RPB && tid >= d) ? sscan[tid - d] : 0;
      __syncthreads();
      if (tid < RPB) sscan[tid] += v;
      __syncthreads();
    }
    if (tid < RPB) rstart[tid + 1] = sscan[tid];
    if (tid == 0) rstart[0] = 0;
    __syncthreads();
    if (tid < RPB) rcur[tid] = rstart[tid];
    __syncthreads();

#pragma unroll
    for (int j = 0; j < QREG; ++j) {
      int i = j * AGG_T + tid;
      if (i < cnt) {
        u64 q = qreg[j];
        int r = (unsigned)(q >> 17) & 63u;
        int pos = atomicAdd(&rcur[r], 1);
        eds[pos] = q;
      }
    }
    __syncthreads();

    // aggregate: wave w handles rows w, w+8, ... ; lane owns 2 channels
    for (int r = w; r < RPB; r += AGG_T / 64) {
      int grow = row0 + r;
      if (grow >= N_NODES) break;
      int e = rstart[r], e2 = rstart[r + 1];
      float ax = 0.f, ay = 0.f;
      for (; e + 7 < e2; e += 8) {
        u64 q[8];
#pragma unroll
        for (int j = 0; j < 8; ++j) q[j] = eds[e + j];
        unsigned g[8];
#pragma unroll
        for (int j = 0; j < 8; ++j)
          g[j] = h32[(size_t)(unsigned)(q[j] & 0x1FFFFu) * 64 + lane];
#pragma unroll
        for (int j = 0; j < 8; ++j) {
          float v = __int_as_float((int)(q[j] >> 32));
          ax += v * __uint_as_float(g[j] << 16);
          ay += v * __uint_as_float(g[j] & 0xFFFF0000u);
        }
      }
      for (; e < e2; ++e) {
        u64 q = eds[e];
        unsigned u = h32[(size_t)(unsigned)(q & 0x1FFFFu) * 64 + lane];
        float v = __int_as_float((int)(q >> 32));
        ax += v * __uint_as_float(u << 16);
        ay += v * __uint_as_float(u & 0xFFFF0000u);
      }
      reinterpret_cast<float2*>(out)[(size_t)grow * 64 + lane] =
          make_float2(ax, ay);
    }
  } else {
    // fallback (statistically unreachable): zero rows then global atomics
    for (int i = tid; i < RPB * 64; i += AGG_T) {
      int grow = row0 + (i >> 6);
      if (grow < N_NODES)
        reinterpret_cast<float2*>(out)[(size_t)grow * 64 + (i & 63)] =
            make_float2(0.f, 0.f);
    }
    __syncthreads();
    for (int i = w; i < cnt; i += AGG_T / 64) {
      u64 q = tmp[base + i];
      int r = (unsigned)(q >> 17) & 63u;
      unsigned col = (unsigned)(q & 0x1FFFFu);
      float v = __int_as_float((int)(q >> 32));
      unsigned u = h32[(size_t)col * 64 + lane];
      if (row0 + r < N_NODES) {
        atomicAdd(out + (size_t)(row0 + r) * OUT_CH + lane * 2,
                  v * __uint_as_float(u << 16));
        atomicAdd(out + (size_t)(row0 + r) * OUT_CH + lane * 2 + 1,
                  v * __uint_as_float(u & 0xFFFF0000u));
      }
    }
  }
}

extern "C" void kernel_launch(void* const* d_in, const int* in_sizes, int n_in,
                              void* d_out, int out_size, void* d_ws,
                              size_t ws_size, hipStream_t stream) {
  const float* x    = (const float*)d_in[0];
  const float* W    = (const float*)d_in[1];
  const float* b    = (const float*)d_in[2];
  const int* erow   = (const int*)d_in[3];
  const int* ecol   = (const int*)d_in[4];
  const float* eval = (const float*)d_in[5];
  float* out = (float*)d_out;

  // Workspace (~52.9 MB):
  //   hb:    [0, 25.6MB)          N_NODES*OUT_CH bf16
  //   tmp:   [25.6MB, +25.6MB)    N_EDGES u64 (bucket-partitioned edges)
  //   scanA: [51.2MB, +1600512B)  NBUCKET*NBLK ints
  //   bsum:  [+6252B]             NBUCKET ints
  //   wt:    [+64KB]              W^T bf16 [128][256]
  char* wsb = (char*)d_ws;
  ushort_t* hb  = (ushort_t*)(wsb);
  u64* tmp      = (u64*)(wsb + 25600000);
  int* scanA    = (int*)(wsb + 51200000);
  int* bsum     = (int*)(wsb + 52800512);
  ushort_t* wt  = (ushort_t*)(wsb + 52806764 + 4);  // align 8

  // 1) W transpose+bf16 (tiny)
  wt_prep_kernel<<<32, 256, 0, stream>>>(W, wt);

  // 2) fused: histA (blocks 0..255, overlapped) + GEMM (blocks 256..3380)
  gemm_hist_kernel<<<NBLK + GEMM_BLKS, 256, 0, stream>>>(x, wt, b, hb, erow,
                                                         scanA);

  // 3) scan + partition
  scanA_partial<<<NBUCKET, 256, 0, stream>>>(scanA, bsum);
  scanA_bsums<<<1, 1024, 0, stream>>>(bsum);
  scanA_apply<<<NBUCKET, 256, 0, stream>>>(scanA, bsum);
  sortscatter_kernel<<<NBLK, SS_T, 0, stream>>>(erow, ecol, eval, scanA, tmp);

  // 4) fused in-LDS row-sort + aggregate + store
  bucket_agg_kernel<<<NBUCKET, AGG_T, 0, stream>>>(hb, tmp, scanA, out);
}